// Round 1
// baseline (467.102 us; speedup 1.0000x reference)
//
#include <hip/hip_runtime.h>

// Problem constants
#define NROWS 16384   // 8*2048 tokens
#define DM    1024    // d_model
#define CD    64      // code depth
#define NC    2048    // num codes
#define KC    2047    // codes excluding index 0
#define NB    8       // batch
#define DECAY 0.99f

// d_out layout (floats, concatenated in reference return order)
#define OUT_HARD   0
#define OUT_IDX    1048576
#define OUT_COMMIT 1064960
#define OUT_EMB    1064961
#define OUT_CB     1064962
#define OUT_CS     1196034
#define OUT_CSUM   1198082

// d_ws layout (float offsets); total 1,232,889 floats ~ 4.93 MB
#define WS_Z      0
#define WS_IDX    (WS_Z + NROWS*CD)       // int[16384]
#define WS_CN2    (WS_IDX + NROWS)        // float[2048], [2047]=+INF pad
#define WS_BINC   (WS_CN2 + NC)           // uint[2048]
#define WS_SUMS   (WS_BINC + NC)          // float[2048*64]
#define WS_CDIST  (WS_SUMS + NC*CD)       // uint[8*2047] (clamped d2 bits)
#define WS_COMMIT (WS_CDIST + NB*KC)      // float[1]
#define WS_ZN2    (WS_COMMIT + 1)         // float[16384]

#define F32_INF_BITS 0x7F800000u

// ---------------------------------------------------------------- K0: init
__global__ __launch_bounds__(256) void k0_init(const float* __restrict__ cb,
                                               float* __restrict__ ws) {
  int i = blockIdx.x * 256 + threadIdx.x;
  if (i < NC * CD) (ws + WS_SUMS)[i] = 0.0f;
  if (i < NC) {
    ((unsigned*)(ws + WS_BINC))[i] = 0u;
    float cn2;
    if (i < KC) {
      const float* c = cb + (size_t)(i + 1) * CD;
      float s0 = 0.f, s1 = 0.f;
      #pragma unroll
      for (int d = 0; d < CD; d += 2) { s0 = fmaf(c[d], c[d], s0); s1 = fmaf(c[d+1], c[d+1], s1); }
      cn2 = s0 + s1;
    } else {
      cn2 = __uint_as_float(F32_INF_BITS);
    }
    (ws + WS_CN2)[i] = cn2;
  }
  if (i < NB * KC) ((unsigned*)(ws + WS_CDIST))[i] = F32_INF_BITS;
  if (i == 0) (ws + WS_COMMIT)[0] = 0.f;
}

// --------------------------------------------- K1: z = norm(x @ W^T + b)
// 256 threads, 64-row tile, K-tiles of 64, reg-staged prefetch.
__global__ __launch_bounds__(256) void k1_down(const float* __restrict__ x,
                                               const float* __restrict__ W,
                                               const float* __restrict__ bdown,
                                               float* __restrict__ ws) {
  __shared__ float xs[64][68];
  __shared__ float wls[64][68];
  const int t = threadIdx.x;
  const int row0 = blockIdx.x * 64;
  const int tx = t & 15, ty = t >> 4;

  int pr[4], pseg[4];
  #pragma unroll
  for (int it = 0; it < 4; ++it) { int c = t + it * 256; pr[it] = c >> 4; pseg[it] = c & 15; }

  float4 px[4], pw[4];
  #pragma unroll
  for (int it = 0; it < 4; ++it) {
    px[it] = *(const float4*)(x + (size_t)(row0 + pr[it]) * DM + pseg[it] * 4);
    pw[it] = *(const float4*)(W + (size_t)pr[it] * DM + pseg[it] * 4);
  }

  float acc[4][4];
  #pragma unroll
  for (int i = 0; i < 4; i++)
    #pragma unroll
    for (int j = 0; j < 4; j++) acc[i][j] = 0.f;

  for (int kt = 0; kt < 16; ++kt) {
    __syncthreads();
    #pragma unroll
    for (int it = 0; it < 4; ++it) {
      *(float4*)(&xs[pr[it]][pseg[it] * 4]) = px[it];
      *(float4*)(&wls[pr[it]][pseg[it] * 4]) = pw[it];
    }
    __syncthreads();
    if (kt < 15) {
      const int k0 = (kt + 1) * 64;
      #pragma unroll
      for (int it = 0; it < 4; ++it) {
        px[it] = *(const float4*)(x + (size_t)(row0 + pr[it]) * DM + k0 + pseg[it] * 4);
        pw[it] = *(const float4*)(W + (size_t)pr[it] * DM + k0 + pseg[it] * 4);
      }
    }
    float loc[4][4];
    #pragma unroll
    for (int i = 0; i < 4; i++)
      #pragma unroll
      for (int j = 0; j < 4; j++) loc[i][j] = 0.f;
    #pragma unroll 4
    for (int k = 0; k < 64; k += 4) {
      float4 xv[4], wv[4];
      #pragma unroll
      for (int i = 0; i < 4; i++) xv[i] = *(const float4*)(&xs[ty * 4 + i][k]);
      #pragma unroll
      for (int j = 0; j < 4; j++) wv[j] = *(const float4*)(&wls[tx * 4 + j][k]);
      #pragma unroll
      for (int i = 0; i < 4; i++)
        #pragma unroll
        for (int j = 0; j < 4; j++)
          loc[i][j] += xv[i].x * wv[j].x + xv[i].y * wv[j].y + xv[i].z * wv[j].z + xv[i].w * wv[j].w;
    }
    #pragma unroll
    for (int i = 0; i < 4; i++)
      #pragma unroll
      for (int j = 0; j < 4; j++) acc[i][j] += loc[i][j];  // per-tile partial: pairwise-ish accuracy
  }

  #pragma unroll
  for (int j = 0; j < 4; j++) {
    float bj = bdown[tx * 4 + j];
    #pragma unroll
    for (int i = 0; i < 4; i++) acc[i][j] += bj;
  }

  float* z = ws + WS_Z;
  float* zn2 = ws + WS_ZN2;
  #pragma unroll
  for (int i = 0; i < 4; i++) {
    float ss = acc[i][0] * acc[i][0] + acc[i][1] * acc[i][1] +
               acc[i][2] * acc[i][2] + acc[i][3] * acc[i][3];
    #pragma unroll
    for (int m = 1; m < 16; m <<= 1) ss += __shfl_xor(ss, m, 64);
    float inv = 1.0f / sqrtf(ss);   // uniform per-row scale: argmin-safe
    float4 zv;
    zv.x = acc[i][0] * inv; zv.y = acc[i][1] * inv;
    zv.z = acc[i][2] * inv; zv.w = acc[i][3] * inv;
    int row = row0 + ty * 4 + i;
    *(float4*)(z + (size_t)row * CD + tx * 4) = zv;
    if (tx == 0) zn2[row] = ss * inv * inv;
  }
}

// ---- K2: fused distance GEMM + per-row argmin + per-(b,code) column-min
// 512 threads (8 waves), 64-row tile x 128-code k-tiles, transposed LDS.
__global__ __launch_bounds__(512) void k2_dist(const float* __restrict__ cb,
                                               float* __restrict__ ws,
                                               float* __restrict__ out) {
  __shared__ float zT[64][68];    // [d][row]
  __shared__ float cT[64][132];   // [d][code]
  __shared__ float cn2s[128];
  __shared__ float zn2s[64];
  __shared__ unsigned colmin[128];

  const int t = threadIdx.x;
  const int row0 = blockIdx.x * 64;
  const int batch = row0 >> 11;
  const int tx = t & 31, ty = t >> 5;
  const float* z = ws + WS_Z;
  const float* cn2 = ws + WS_CN2;
  unsigned* cdist = (unsigned*)(ws + WS_CDIST) + (size_t)batch * KC;

  // stage zT (once)
  #pragma unroll
  for (int it = 0; it < 2; ++it) {
    int c = t + it * 512;
    int r = c >> 4, seg = c & 15;
    float4 v = *(const float4*)(z + (size_t)(row0 + r) * CD + seg * 4);
    zT[seg * 4 + 0][r] = v.x; zT[seg * 4 + 1][r] = v.y;
    zT[seg * 4 + 2][r] = v.z; zT[seg * 4 + 3][r] = v.w;
  }
  if (t < 64) zn2s[t] = (ws + WS_ZN2)[row0 + t];

  int cjj[4], cseg[4];
  #pragma unroll
  for (int it = 0; it < 4; ++it) { int c = t + it * 512; cjj[it] = c >> 4; cseg[it] = c & 15; }

  float4 pre[4];
  #pragma unroll
  for (int it = 0; it < 4; ++it) {
    int jg = cjj[it];   // tile 0
    pre[it] = (jg < KC) ? *(const float4*)(cb + (size_t)(jg + 1) * CD + cseg[it] * 4)
                        : make_float4(0.f, 0.f, 0.f, 0.f);
  }

  float bestv[4];
  int besti[4];
  #pragma unroll
  for (int i = 0; i < 4; i++) { bestv[i] = __uint_as_float(F32_INF_BITS); besti[i] = 0; }

  for (int tile = 0; tile < 16; ++tile) {
    __syncthreads();  // prev compute + prev colmin drain done
    #pragma unroll
    for (int it = 0; it < 4; ++it) {
      cT[cseg[it] * 4 + 0][cjj[it]] = pre[it].x;
      cT[cseg[it] * 4 + 1][cjj[it]] = pre[it].y;
      cT[cseg[it] * 4 + 2][cjj[it]] = pre[it].z;
      cT[cseg[it] * 4 + 3][cjj[it]] = pre[it].w;
    }
    if (t < 128) { cn2s[t] = cn2[tile * 128 + t]; colmin[t] = F32_INF_BITS; }
    __syncthreads();
    if (tile < 15) {
      #pragma unroll
      for (int it = 0; it < 4; ++it) {
        int jg = (tile + 1) * 128 + cjj[it];
        pre[it] = (jg < KC) ? *(const float4*)(cb + (size_t)(jg + 1) * CD + cseg[it] * 4)
                            : make_float4(0.f, 0.f, 0.f, 0.f);
      }
    }

    float dot[4][4];
    #pragma unroll
    for (int i = 0; i < 4; i++)
      #pragma unroll
      for (int j = 0; j < 4; j++) dot[i][j] = 0.f;
    #pragma unroll 8
    for (int d = 0; d < 64; ++d) {
      float4 zv = *(const float4*)(&zT[d][ty * 4]);
      float4 cv = *(const float4*)(&cT[d][tx * 4]);
      float zz[4] = {zv.x, zv.y, zv.z, zv.w};
      float cc[4] = {cv.x, cv.y, cv.z, cv.w};
      #pragma unroll
      for (int i = 0; i < 4; i++)
        #pragma unroll
        for (int j = 0; j < 4; j++) dot[i][j] = fmaf(zz[i], cc[j], dot[i][j]);
    }

    // score = cn2 - 2*dot (znorm2 constant per row: argmin-equivalent)
    #pragma unroll
    for (int jl = 0; jl < 4; jl++) {
      int jloc = tx * 4 + jl;
      int jg = tile * 128 + jloc;
      float c2 = cn2s[jloc];
      float colv = __uint_as_float(F32_INF_BITS);
      #pragma unroll
      for (int i = 0; i < 4; i++) {
        float s = fmaf(-2.f, dot[i][jl], c2);
        if (s < bestv[i]) { bestv[i] = s; besti[i] = jg; }  // ascending jg => first-index ties
        float v = zn2s[ty * 4 + i] + s;
        v = v < 0.f ? 0.f : v;        // clamp(d2,0): monotone under sqrt/min
        colv = v < colv ? v : colv;
      }
      atomicMin(&colmin[jloc], __float_as_uint(colv));
    }
    __syncthreads();
    if (t < 128) {
      int jg = tile * 128 + t;
      if (jg < KC) atomicMin(&cdist[jg], colmin[t]);
    }
  }

  // argmin reduce across the 32-lane code group (same wave)
  #pragma unroll
  for (int m = 1; m < 32; m <<= 1) {
    #pragma unroll
    for (int i = 0; i < 4; i++) {
      float ov = __shfl_xor(bestv[i], m, 64);
      int oi = __shfl_xor(besti[i], m, 64);
      if (ov < bestv[i] || (ov == bestv[i] && oi < besti[i])) { bestv[i] = ov; besti[i] = oi; }
    }
  }
  if (tx == 0) {
    #pragma unroll
    for (int i = 0; i < 4; i++) {
      int row = row0 + ty * 4 + i;
      int idx = besti[i] + 1;
      ((int*)(ws + WS_IDX))[row] = idx;
      out[OUT_IDX + row] = (float)idx;
    }
  }
}

// ------- K3: gather hard codes, commitment loss, scatter sums/bincounts
__global__ __launch_bounds__(256) void k3_scatter(const float* __restrict__ cb,
                                                  float* __restrict__ ws,
                                                  float* __restrict__ out) {
  const int t = threadIdx.x;
  const int lane = t & 63;
  const int w = t >> 6;
  const int row = blockIdx.x * 4 + w;
  const int idx = ((const int*)(ws + WS_IDX))[row];
  const float c = cb[(size_t)idx * CD + lane];
  const float zv = (ws + WS_Z)[(size_t)row * CD + lane];
  out[OUT_HARD + (size_t)row * CD + lane] = zv + (c - zv);  // matches z + sg(hard - z)
  float d = c - zv;
  float sq = d * d;
  #pragma unroll
  for (int m = 1; m < 64; m <<= 1) sq += __shfl_xor(sq, m, 64);
  if (lane == 0) {
    atomicAdd(ws + WS_COMMIT, sq);
    atomicAdd((unsigned*)(ws + WS_BINC) + idx, 1u);
  }
  atomicAdd(ws + WS_SUMS + (size_t)idx * CD + lane, zv);
}

// --------------------------- K4: EMA finalize + losses (single block)
__global__ __launch_bounds__(1024) void k4_final(const float* __restrict__ cb,
                                                 const float* __restrict__ cs_in,
                                                 const float* __restrict__ csum_in,
                                                 float* __restrict__ ws,
                                                 float* __restrict__ out) {
  __shared__ float red[1024];
  __shared__ float ncs_s[NC];
  const int t = threadIdx.x;
  const unsigned* binc = (const unsigned*)(ws + WS_BINC);

  // new_cs and n
  float npart = 0.f;
  for (int i = t; i < NC; i += 1024) {
    float nc = DECAY * cs_in[i] + (1.f - DECAY) * (float)binc[i];
    out[OUT_CS + i] = nc;
    ncs_s[i] = nc;
    npart += nc;
  }
  red[t] = npart; __syncthreads();
  for (int s = 512; s > 0; s >>= 1) { if (t < s) red[t] += red[t + s]; __syncthreads(); }
  float n = red[0]; __syncthreads();

  // unused-code loss
  const unsigned* cdist = (const unsigned*)(ws + WS_CDIST);
  float lsum = 0.f, ccount = 0.f;
  for (int j = t; j < KC; j += 1024) {
    if (binc[j + 1] == 0u) {
      ccount += 1.f;
      float srow = 0.f;
      #pragma unroll
      for (int b = 0; b < NB; b++) srow += sqrtf(__uint_as_float(cdist[b * KC + j]));
      lsum += srow;
    }
  }
  red[t] = lsum; __syncthreads();
  for (int s = 512; s > 0; s >>= 1) { if (t < s) red[t] += red[t + s]; __syncthreads(); }
  float totloss = red[0]; __syncthreads();
  red[t] = ccount; __syncthreads();
  for (int s = 512; s > 0; s >>= 1) { if (t < s) red[t] += red[t + s]; __syncthreads(); }
  float cnt = red[0] * (float)NB;
  if (t == 0) {
    out[OUT_COMMIT] = (ws + WS_COMMIT)[0] / (float)(NROWS * CD);
    out[OUT_EMB] = totloss / fmaxf(cnt, 1.f);
  }
  __syncthreads();

  // new_csum, centroids, new_cb
  const float* sums = ws + WS_SUMS;
  const float denom = n + (float)NC * 1e-5f;
  for (int e = t; e < NC * CD; e += 1024) {
    int k = e >> 6;
    float ncsum = DECAY * csum_in[e] + (1.f - DECAY) * sums[e];
    out[OUT_CSUM + e] = ncsum;
    float smoothed = (ncs_s[k] + 1e-5f) * n / denom;
    float cent = ncsum / smoothed;
    float v = (binc[k] != 0u) ? cent : cb[e];
    if (k == 0) v = 0.f;
    out[OUT_CB + e] = v;
  }
}

extern "C" void kernel_launch(void* const* d_in, const int* in_sizes, int n_in,
                              void* d_out, int out_size, void* d_ws, size_t ws_size,
                              hipStream_t stream) {
  const float* x    = (const float*)d_in[0];
  const float* W    = (const float*)d_in[1];
  const float* b    = (const float*)d_in[2];
  const float* cb   = (const float*)d_in[3];
  const float* cs   = (const float*)d_in[4];
  const float* csum = (const float*)d_in[5];
  float* out = (float*)d_out;
  float* ws  = (float*)d_ws;   // needs ~4.93 MB

  hipLaunchKernelGGL(k0_init,    dim3(512),  dim3(256),  0, stream, cb, ws);
  hipLaunchKernelGGL(k1_down,    dim3(256),  dim3(256),  0, stream, x, W, b, ws);
  hipLaunchKernelGGL(k2_dist,    dim3(256),  dim3(512),  0, stream, cb, ws, out);
  hipLaunchKernelGGL(k3_scatter, dim3(4096), dim3(256),  0, stream, cb, ws, out);
  hipLaunchKernelGGL(k4_final,   dim3(1),    dim3(1024), 0, stream, cb, cs, csum, ws, out);
}

// Round 2
// 202.023 us; speedup vs baseline: 2.3121x; 2.3121x over previous
//
#include <hip/hip_runtime.h>

// Problem constants
#define NROWS 16384   // 8*2048 tokens
#define DM    1024    // d_model
#define CD    64      // code depth
#define NC    2048    // num codes
#define KC    2047    // codes excluding index 0
#define NB    8       // batch
#define DECAY 0.99f

#define K3_BLOCKS 512

// d_out layout (floats, concatenated in reference return order)
#define OUT_HARD   0
#define OUT_IDX    1048576
#define OUT_COMMIT 1064960
#define OUT_EMB    1064961
#define OUT_CB     1064962
#define OUT_CS     1196034
#define OUT_CSUM   1198082

// d_ws layout (float offsets)
#define WS_Z      0
#define WS_IDX    (WS_Z + NROWS*CD)        // int[16384]
#define WS_CN2    (WS_IDX + NROWS)         // float[2048], [2047]=+INF pad
#define WS_BINC   (WS_CN2 + NC)            // uint[2048]
#define WS_SUMS   (WS_BINC + NC)           // float[2048*64]
#define WS_CDIST  (WS_SUMS + NC*CD)        // uint[8*2047] (clamped d2 bits)
#define WS_COMMIT (WS_CDIST + NB*KC)       // float[K3_BLOCKS] per-block partials
#define WS_ZN2    (WS_COMMIT + K3_BLOCKS)  // float[16384]
#define WS_N      (WS_ZN2 + NROWS)         // float[1]

#define F32_INF_BITS 0x7F800000u

// ---------------------------------------------------------------- K0: init
__global__ __launch_bounds__(256) void k0_init(const float* __restrict__ cb,
                                               float* __restrict__ ws) {
  int i = blockIdx.x * 256 + threadIdx.x;
  if (i < NC * CD) (ws + WS_SUMS)[i] = 0.0f;
  if (i < NC) {
    ((unsigned*)(ws + WS_BINC))[i] = 0u;
    float cn2;
    if (i < KC) {
      const float* c = cb + (size_t)(i + 1) * CD;
      float s0 = 0.f, s1 = 0.f;
      #pragma unroll
      for (int d = 0; d < CD; d += 2) { s0 = fmaf(c[d], c[d], s0); s1 = fmaf(c[d+1], c[d+1], s1); }
      cn2 = s0 + s1;
    } else {
      cn2 = __uint_as_float(F32_INF_BITS);
    }
    (ws + WS_CN2)[i] = cn2;
  }
  if (i < NB * KC) ((unsigned*)(ws + WS_CDIST))[i] = F32_INF_BITS;
}

// --------------------------------------------- K1: z = norm(x @ W^T + b)
// 256 threads, 64-row tile, K-tiles of 64, reg-staged prefetch.
__global__ __launch_bounds__(256) void k1_down(const float* __restrict__ x,
                                               const float* __restrict__ W,
                                               const float* __restrict__ bdown,
                                               float* __restrict__ ws) {
  __shared__ float xs[64][68];
  __shared__ float wls[64][68];
  const int t = threadIdx.x;
  const int row0 = blockIdx.x * 64;
  const int tx = t & 15, ty = t >> 4;

  int pr[4], pseg[4];
  #pragma unroll
  for (int it = 0; it < 4; ++it) { int c = t + it * 256; pr[it] = c >> 4; pseg[it] = c & 15; }

  float4 px[4], pw[4];
  #pragma unroll
  for (int it = 0; it < 4; ++it) {
    px[it] = *(const float4*)(x + (size_t)(row0 + pr[it]) * DM + pseg[it] * 4);
    pw[it] = *(const float4*)(W + (size_t)pr[it] * DM + pseg[it] * 4);
  }

  float acc[4][4];
  #pragma unroll
  for (int i = 0; i < 4; i++)
    #pragma unroll
    for (int j = 0; j < 4; j++) acc[i][j] = 0.f;

  for (int kt = 0; kt < 16; ++kt) {
    __syncthreads();
    #pragma unroll
    for (int it = 0; it < 4; ++it) {
      *(float4*)(&xs[pr[it]][pseg[it] * 4]) = px[it];
      *(float4*)(&wls[pr[it]][pseg[it] * 4]) = pw[it];
    }
    __syncthreads();
    if (kt < 15) {
      const int k0 = (kt + 1) * 64;
      #pragma unroll
      for (int it = 0; it < 4; ++it) {
        px[it] = *(const float4*)(x + (size_t)(row0 + pr[it]) * DM + k0 + pseg[it] * 4);
        pw[it] = *(const float4*)(W + (size_t)pr[it] * DM + k0 + pseg[it] * 4);
      }
    }
    float loc[4][4];
    #pragma unroll
    for (int i = 0; i < 4; i++)
      #pragma unroll
      for (int j = 0; j < 4; j++) loc[i][j] = 0.f;
    #pragma unroll 4
    for (int k = 0; k < 64; k += 4) {
      float4 xv[4], wv[4];
      #pragma unroll
      for (int i = 0; i < 4; i++) xv[i] = *(const float4*)(&xs[ty * 4 + i][k]);
      #pragma unroll
      for (int j = 0; j < 4; j++) wv[j] = *(const float4*)(&wls[tx * 4 + j][k]);
      #pragma unroll
      for (int i = 0; i < 4; i++)
        #pragma unroll
        for (int j = 0; j < 4; j++)
          loc[i][j] += xv[i].x * wv[j].x + xv[i].y * wv[j].y + xv[i].z * wv[j].z + xv[i].w * wv[j].w;
    }
    #pragma unroll
    for (int i = 0; i < 4; i++)
      #pragma unroll
      for (int j = 0; j < 4; j++) acc[i][j] += loc[i][j];  // per-tile partial: pairwise-ish accuracy
  }

  #pragma unroll
  for (int j = 0; j < 4; j++) {
    float bj = bdown[tx * 4 + j];
    #pragma unroll
    for (int i = 0; i < 4; i++) acc[i][j] += bj;
  }

  float* z = ws + WS_Z;
  float* zn2 = ws + WS_ZN2;
  #pragma unroll
  for (int i = 0; i < 4; i++) {
    float ss = acc[i][0] * acc[i][0] + acc[i][1] * acc[i][1] +
               acc[i][2] * acc[i][2] + acc[i][3] * acc[i][3];
    #pragma unroll
    for (int m = 1; m < 16; m <<= 1) ss += __shfl_xor(ss, m, 64);
    float inv = 1.0f / sqrtf(ss);   // uniform per-row scale: argmin-safe
    float4 zv;
    zv.x = acc[i][0] * inv; zv.y = acc[i][1] * inv;
    zv.z = acc[i][2] * inv; zv.w = acc[i][3] * inv;
    int row = row0 + ty * 4 + i;
    *(float4*)(z + (size_t)row * CD + tx * 4) = zv;
    if (tx == 0) zn2[row] = ss * inv * inv;
  }
}

// ---- K2: fused distance GEMM + per-row argmin + per-(b,code) column-min
// 512 threads (8 waves), 64-row tile x 128-code k-tiles, transposed LDS.
__global__ __launch_bounds__(512) void k2_dist(const float* __restrict__ cb,
                                               float* __restrict__ ws,
                                               float* __restrict__ out) {
  __shared__ float zT[64][68];    // [d][row]
  __shared__ float cT[64][132];   // [d][code]
  __shared__ float cn2s[128];
  __shared__ float zn2s[64];
  __shared__ unsigned colmin[128];

  const int t = threadIdx.x;
  const int row0 = blockIdx.x * 64;
  const int batch = row0 >> 11;
  const int tx = t & 31, ty = t >> 5;
  const float* z = ws + WS_Z;
  const float* cn2 = ws + WS_CN2;
  unsigned* cdist = (unsigned*)(ws + WS_CDIST) + (size_t)batch * KC;

  // stage zT (once)
  #pragma unroll
  for (int it = 0; it < 2; ++it) {
    int c = t + it * 512;
    int r = c >> 4, seg = c & 15;
    float4 v = *(const float4*)(z + (size_t)(row0 + r) * CD + seg * 4);
    zT[seg * 4 + 0][r] = v.x; zT[seg * 4 + 1][r] = v.y;
    zT[seg * 4 + 2][r] = v.z; zT[seg * 4 + 3][r] = v.w;
  }
  if (t < 64) zn2s[t] = (ws + WS_ZN2)[row0 + t];

  int cjj[4], cseg[4];
  #pragma unroll
  for (int it = 0; it < 4; ++it) { int c = t + it * 512; cjj[it] = c >> 4; cseg[it] = c & 15; }

  float4 pre[4];
  #pragma unroll
  for (int it = 0; it < 4; ++it) {
    int jg = cjj[it];   // tile 0
    pre[it] = (jg < KC) ? *(const float4*)(cb + (size_t)(jg + 1) * CD + cseg[it] * 4)
                        : make_float4(0.f, 0.f, 0.f, 0.f);
  }

  float bestv[4];
  int besti[4];
  #pragma unroll
  for (int i = 0; i < 4; i++) { bestv[i] = __uint_as_float(F32_INF_BITS); besti[i] = 0; }

  for (int tile = 0; tile < 16; ++tile) {
    __syncthreads();  // prev compute + prev colmin drain done
    #pragma unroll
    for (int it = 0; it < 4; ++it) {
      cT[cseg[it] * 4 + 0][cjj[it]] = pre[it].x;
      cT[cseg[it] * 4 + 1][cjj[it]] = pre[it].y;
      cT[cseg[it] * 4 + 2][cjj[it]] = pre[it].z;
      cT[cseg[it] * 4 + 3][cjj[it]] = pre[it].w;
    }
    if (t < 128) { cn2s[t] = cn2[tile * 128 + t]; colmin[t] = F32_INF_BITS; }
    __syncthreads();
    if (tile < 15) {
      #pragma unroll
      for (int it = 0; it < 4; ++it) {
        int jg = (tile + 1) * 128 + cjj[it];
        pre[it] = (jg < KC) ? *(const float4*)(cb + (size_t)(jg + 1) * CD + cseg[it] * 4)
                            : make_float4(0.f, 0.f, 0.f, 0.f);
      }
    }

    float dot[4][4];
    #pragma unroll
    for (int i = 0; i < 4; i++)
      #pragma unroll
      for (int j = 0; j < 4; j++) dot[i][j] = 0.f;
    #pragma unroll 8
    for (int d = 0; d < 64; ++d) {
      float4 zv = *(const float4*)(&zT[d][ty * 4]);
      float4 cv = *(const float4*)(&cT[d][tx * 4]);
      float zz[4] = {zv.x, zv.y, zv.z, zv.w};
      float cc[4] = {cv.x, cv.y, cv.z, cv.w};
      #pragma unroll
      for (int i = 0; i < 4; i++)
        #pragma unroll
        for (int j = 0; j < 4; j++) dot[i][j] = fmaf(zz[i], cc[j], dot[i][j]);
    }

    // score = cn2 - 2*dot (znorm2 constant per row: argmin-equivalent)
    #pragma unroll
    for (int jl = 0; jl < 4; jl++) {
      int jloc = tx * 4 + jl;
      int jg = tile * 128 + jloc;
      float c2 = cn2s[jloc];
      float colv = __uint_as_float(F32_INF_BITS);
      #pragma unroll
      for (int i = 0; i < 4; i++) {
        float s = fmaf(-2.f, dot[i][jl], c2);
        if (s < bestv[i]) { bestv[i] = s; besti[i] = jg; }  // ascending jg => first-index ties
        float v = zn2s[ty * 4 + i] + s;
        v = v < 0.f ? 0.f : v;        // clamp(d2,0): monotone under sqrt/min
        colv = v < colv ? v : colv;
      }
      atomicMin(&colmin[jloc], __float_as_uint(colv));
    }
    __syncthreads();
    if (t < 128) {
      int jg = tile * 128 + t;
      if (jg < KC) atomicMin(&cdist[jg], colmin[t]);
    }
  }

  // argmin reduce across the 32-lane code group (same wave)
  #pragma unroll
  for (int m = 1; m < 32; m <<= 1) {
    #pragma unroll
    for (int i = 0; i < 4; i++) {
      float ov = __shfl_xor(bestv[i], m, 64);
      int oi = __shfl_xor(besti[i], m, 64);
      if (ov < bestv[i] || (ov == bestv[i] && oi < besti[i])) { bestv[i] = ov; besti[i] = oi; }
    }
  }
  if (tx == 0) {
    #pragma unroll
    for (int i = 0; i < 4; i++) {
      int row = row0 + ty * 4 + i;
      int idx = besti[i] + 1;
      ((int*)(ws + WS_IDX))[row] = idx;
      out[OUT_IDX + row] = (float)idx;
    }
  }
}

// ------- K3: gather hard codes, commitment partials, scatter sums/bincounts
// K3_BLOCKS blocks x 256 threads (4 waves); each wave handles 8 rows.
// Commitment: per-thread accum -> block reduce -> ONE plain store per block.
__global__ __launch_bounds__(256) void k3_scatter(const float* __restrict__ cb,
                                                  float* __restrict__ ws,
                                                  float* __restrict__ out) {
  const int t = threadIdx.x;
  const int lane = t & 63;
  const int w = t >> 6;
  const int rowbase = blockIdx.x * 32 + w * 8;
  const float* z = ws + WS_Z;
  const int* idxp = (const int*)(ws + WS_IDX);

  // prefetch indices (independent loads, breaks the dependent chain)
  int idx[8];
  #pragma unroll
  for (int r = 0; r < 8; ++r) idx[r] = idxp[rowbase + r];

  float sq = 0.f;
  #pragma unroll
  for (int r = 0; r < 8; ++r) {
    const int row = rowbase + r;
    const float c = cb[(size_t)idx[r] * CD + lane];
    const float zv = z[(size_t)row * CD + lane];
    out[OUT_HARD + (size_t)row * CD + lane] = zv + (c - zv);  // matches z + sg(hard - z)
    const float d = c - zv;
    sq = fmaf(d, d, sq);
    atomicAdd(ws + WS_SUMS + (size_t)idx[r] * CD + lane, zv);
    if (lane == 0) atomicAdd((unsigned*)(ws + WS_BINC) + idx[r], 1u);
  }

  // block-reduce commitment partial; one store per block (no same-addr atomics)
  __shared__ float red[4];
  #pragma unroll
  for (int m = 1; m < 64; m <<= 1) sq += __shfl_xor(sq, m, 64);
  if (lane == 0) red[w] = sq;
  __syncthreads();
  if (t == 0) (ws + WS_COMMIT)[blockIdx.x] = red[0] + red[1] + red[2] + red[3];
}

// --------- K4a: new_cs + n + losses (single block, small data only)
__global__ __launch_bounds__(1024) void k4a_stats(const float* __restrict__ cs_in,
                                                  float* __restrict__ ws,
                                                  float* __restrict__ out) {
  __shared__ float red[1024];
  const int t = threadIdx.x;
  const unsigned* binc = (const unsigned*)(ws + WS_BINC);

  // new_cs and n
  float npart = 0.f;
  #pragma unroll
  for (int i = t; i < NC; i += 1024) {
    float nc = DECAY * cs_in[i] + (1.f - DECAY) * (float)binc[i];
    out[OUT_CS + i] = nc;
    npart += nc;
  }
  red[t] = npart; __syncthreads();
  for (int s = 512; s > 0; s >>= 1) { if (t < s) red[t] += red[t + s]; __syncthreads(); }
  if (t == 0) (ws + WS_N)[0] = red[0];
  __syncthreads();

  // commitment: reduce per-block partials
  float cpart = 0.f;
  for (int j = t; j < K3_BLOCKS; j += 1024) cpart += (ws + WS_COMMIT)[j];
  red[t] = cpart; __syncthreads();
  for (int s = 512; s > 0; s >>= 1) { if (t < s) red[t] += red[t + s]; __syncthreads(); }
  float commit = red[0]; __syncthreads();

  // unused-code loss
  const unsigned* cdist = (const unsigned*)(ws + WS_CDIST);
  float lsum = 0.f, ccount = 0.f;
  for (int j = t; j < KC; j += 1024) {
    if (binc[j + 1] == 0u) {
      ccount += 1.f;
      float srow = 0.f;
      #pragma unroll
      for (int b = 0; b < NB; b++) srow += sqrtf(__uint_as_float(cdist[b * KC + j]));
      lsum += srow;
    }
  }
  red[t] = lsum; __syncthreads();
  for (int s = 512; s > 0; s >>= 1) { if (t < s) red[t] += red[t + s]; __syncthreads(); }
  float totloss = red[0]; __syncthreads();
  red[t] = ccount; __syncthreads();
  for (int s = 512; s > 0; s >>= 1) { if (t < s) red[t] += red[t + s]; __syncthreads(); }
  float cnt = red[0] * (float)NB;
  if (t == 0) {
    out[OUT_COMMIT] = commit / (float)(NROWS * CD);
    out[OUT_EMB] = totloss / fmaxf(cnt, 1.f);
  }
}

// --------- K4b: new_csum, centroids, new_cb (512 blocks x 256)
__global__ __launch_bounds__(256) void k4b_update(const float* __restrict__ cb,
                                                  const float* __restrict__ csum_in,
                                                  const float* __restrict__ ws,
                                                  float* __restrict__ out) {
  const int e = blockIdx.x * 256 + threadIdx.x;   // 0 .. NC*CD-1
  const int k = e >> 6;
  const unsigned* binc = (const unsigned*)(ws + WS_BINC);
  const float n = (ws + WS_N)[0];
  const float denom = n + (float)NC * 1e-5f;

  float ncsum = DECAY * csum_in[e] + (1.f - DECAY) * (ws + WS_SUMS)[e];
  out[OUT_CSUM + e] = ncsum;
  float smoothed = (out[OUT_CS + k] + 1e-5f) * n / denom;
  float cent = ncsum / smoothed;
  float v = (binc[k] != 0u) ? cent : cb[e];
  if (k == 0) v = 0.f;
  out[OUT_CB + e] = v;
}

extern "C" void kernel_launch(void* const* d_in, const int* in_sizes, int n_in,
                              void* d_out, int out_size, void* d_ws, size_t ws_size,
                              hipStream_t stream) {
  const float* x    = (const float*)d_in[0];
  const float* W    = (const float*)d_in[1];
  const float* b    = (const float*)d_in[2];
  const float* cb   = (const float*)d_in[3];
  const float* cs   = (const float*)d_in[4];
  const float* csum = (const float*)d_in[5];
  float* out = (float*)d_out;
  float* ws  = (float*)d_ws;   // needs ~4.94 MB

  hipLaunchKernelGGL(k0_init,    dim3(512),       dim3(256),  0, stream, cb, ws);
  hipLaunchKernelGGL(k1_down,    dim3(256),       dim3(256),  0, stream, x, W, b, ws);
  hipLaunchKernelGGL(k2_dist,    dim3(256),       dim3(512),  0, stream, cb, ws, out);
  hipLaunchKernelGGL(k3_scatter, dim3(K3_BLOCKS), dim3(256),  0, stream, cb, ws, out);
  hipLaunchKernelGGL(k4a_stats,  dim3(1),         dim3(1024), 0, stream, cs, ws, out);
  hipLaunchKernelGGL(k4b_update, dim3(512),       dim3(256),  0, stream, cb, csum, ws, out);
}

// Round 3
// 168.358 us; speedup vs baseline: 2.7744x; 1.2000x over previous
//
#include <hip/hip_runtime.h>

// Problem constants
#define NROWS 16384   // 8*2048 tokens
#define DM    1024    // d_model
#define CD    64      // code depth
#define NC    2048    // num codes
#define KC    2047    // codes excluding index 0
#define NB    8       // batch
#define DECAY 0.99f

#define K3_BLOCKS 512

// d_out layout (floats, concatenated in reference return order)
#define OUT_HARD   0
#define OUT_IDX    1048576
#define OUT_COMMIT 1064960
#define OUT_EMB    1064961
#define OUT_CB     1064962
#define OUT_CS     1196034
#define OUT_CSUM   1198082

// d_ws layout (float offsets)
#define WS_Z      0                          // 1048576 f
#define WS_CN2    1048576                    // 2048 f ([2047]=+INF pad)
#define WS_BINC   1050624                    // 2048 u32
#define WS_SUMS   1052672                    // 131072 f
#define WS_CDIST  1183744                    // 8*2047 u32
#define WS_COMMIT 1200120                    // 512 f per-block partials
#define WS_ZN2    1200632                    // 16384 f
#define WS_N      1217016                    // 1 f (+3 pad)
#define WS_BV     1217020                    // 2*16384 f  per-half best value
#define WS_BI     1249788                    // 2*16384 i32 per-half best idx (+1 applied)
#define WS_IDXM   1282556                    // 16384 i32 merged idx
#define WS_PART   1298940                    // 4*16384*64 f split-K partials (optional)

#define F32_INF_BITS 0x7F800000u

// ---------------------------------------------------------------- K0: init
__global__ __launch_bounds__(256) void k0_init(const float* __restrict__ cb,
                                               float* __restrict__ ws) {
  int i = blockIdx.x * 256 + threadIdx.x;
  if (i < NC * CD) (ws + WS_SUMS)[i] = 0.0f;
  if (i < NC) {
    ((unsigned*)(ws + WS_BINC))[i] = 0u;
    float cn2;
    if (i < KC) {
      const float* c = cb + (size_t)(i + 1) * CD;
      float s0 = 0.f, s1 = 0.f;
      #pragma unroll
      for (int d = 0; d < CD; d += 2) { s0 = fmaf(c[d], c[d], s0); s1 = fmaf(c[d+1], c[d+1], s1); }
      cn2 = s0 + s1;
    } else {
      cn2 = __uint_as_float(F32_INF_BITS);
    }
    (ws + WS_CN2)[i] = cn2;
  }
  if (i < NB * KC) ((unsigned*)(ws + WS_CDIST))[i] = F32_INF_BITS;
}

// ------------- K1 (split-K): partial[kslice] = x[:,ks*256:+256] @ W^T slice
// grid 512 = 128 rowtiles x 4 kslices; 512 threads; 128x64 tile, 4x4/thread.
// LDS 52.2 KB -> 2 blocks/CU -> 16 waves/CU (vs 4 of the legacy version).
__global__ __launch_bounds__(512, 4) void k1_split(const float* __restrict__ x,
                                                   const float* __restrict__ W,
                                                   float* __restrict__ ws) {
  __shared__ float xs[128][68];
  __shared__ float wls[64][68];
  const int t = threadIdx.x;
  const int kslice = blockIdx.x & 3;
  const int row0 = (blockIdx.x >> 2) * 128;
  const int kbase = kslice * 256;
  const int tx = t & 15, ty = t >> 4;   // ty 0..31

  int pr[4], pseg[4];
  #pragma unroll
  for (int it = 0; it < 4; ++it) { int c = t + it * 512; pr[it] = c >> 4; pseg[it] = c & 15; }
  int wr[2], wseg[2];
  #pragma unroll
  for (int it = 0; it < 2; ++it) { int c = t + it * 512; wr[it] = c >> 4; wseg[it] = c & 15; }

  float4 px[4], pw[2];
  #pragma unroll
  for (int it = 0; it < 4; ++it)
    px[it] = *(const float4*)(x + (size_t)(row0 + pr[it]) * DM + kbase + pseg[it] * 4);
  #pragma unroll
  for (int it = 0; it < 2; ++it)
    pw[it] = *(const float4*)(W + (size_t)wr[it] * DM + kbase + wseg[it] * 4);

  float acc[4][4];
  #pragma unroll
  for (int i = 0; i < 4; i++)
    #pragma unroll
    for (int j = 0; j < 4; j++) acc[i][j] = 0.f;

  for (int kt = 0; kt < 4; ++kt) {
    __syncthreads();
    #pragma unroll
    for (int it = 0; it < 4; ++it) *(float4*)(&xs[pr[it]][pseg[it] * 4]) = px[it];
    #pragma unroll
    for (int it = 0; it < 2; ++it) *(float4*)(&wls[wr[it]][wseg[it] * 4]) = pw[it];
    __syncthreads();
    if (kt < 3) {
      const int k0 = kbase + (kt + 1) * 64;
      #pragma unroll
      for (int it = 0; it < 4; ++it)
        px[it] = *(const float4*)(x + (size_t)(row0 + pr[it]) * DM + k0 + pseg[it] * 4);
      #pragma unroll
      for (int it = 0; it < 2; ++it)
        pw[it] = *(const float4*)(W + (size_t)wr[it] * DM + k0 + wseg[it] * 4);
    }
    #pragma unroll 4
    for (int k = 0; k < 64; k += 4) {
      float4 xv[4], wv[4];
      #pragma unroll
      for (int i = 0; i < 4; i++) xv[i] = *(const float4*)(&xs[ty * 4 + i][k]);
      #pragma unroll
      for (int j = 0; j < 4; j++) wv[j] = *(const float4*)(&wls[tx * 4 + j][k]);
      #pragma unroll
      for (int i = 0; i < 4; i++)
        #pragma unroll
        for (int j = 0; j < 4; j++)
          acc[i][j] = fmaf(xv[i].x, wv[j].x, fmaf(xv[i].y, wv[j].y,
                      fmaf(xv[i].z, wv[j].z, fmaf(xv[i].w, wv[j].w, acc[i][j]))));
    }
  }

  float* part = ws + WS_PART + (size_t)kslice * NROWS * CD;
  #pragma unroll
  for (int i = 0; i < 4; i++) {
    int row = row0 + ty * 4 + i;
    float4 v; v.x = acc[i][0]; v.y = acc[i][1]; v.z = acc[i][2]; v.w = acc[i][3];
    *(float4*)(part + (size_t)row * CD + tx * 4) = v;
  }
}

// ------------- K1r: sum 4 partials + bias, row-normalize, write z/zn2
__global__ __launch_bounds__(256) void k1_reduce(const float* __restrict__ bdown,
                                                 float* __restrict__ ws) {
  const int t = threadIdx.x;
  const int tx = t & 15, ty = t >> 4;
  const int row = blockIdx.x * 16 + ty;
  const float* part = ws + WS_PART;
  const size_t off = (size_t)row * CD + tx * 4;

  float4 v0 = *(const float4*)(part + off);
  float4 v1 = *(const float4*)(part + (size_t)1 * NROWS * CD + off);
  float4 v2 = *(const float4*)(part + (size_t)2 * NROWS * CD + off);
  float4 v3 = *(const float4*)(part + (size_t)3 * NROWS * CD + off);
  float4 b  = *(const float4*)(bdown + tx * 4);
  float4 v;
  v.x = (v0.x + v1.x) + (v2.x + v3.x) + b.x;
  v.y = (v0.y + v1.y) + (v2.y + v3.y) + b.y;
  v.z = (v0.z + v1.z) + (v2.z + v3.z) + b.z;
  v.w = (v0.w + v1.w) + (v2.w + v3.w) + b.w;

  float ss = v.x * v.x + v.y * v.y + v.z * v.z + v.w * v.w;
  #pragma unroll
  for (int m = 1; m < 16; m <<= 1) ss += __shfl_xor(ss, m, 64);
  float inv = 1.0f / sqrtf(ss);   // uniform per-row scale: argmin-safe
  float4 zv; zv.x = v.x * inv; zv.y = v.y * inv; zv.z = v.z * inv; zv.w = v.w * inv;
  *(float4*)(ws + WS_Z + off) = zv;
  if (tx == 0) (ws + WS_ZN2)[row] = ss * inv * inv;
}

// ------------- K1 legacy (used only if ws too small for split-K partials)
__global__ __launch_bounds__(256) void k1_down(const float* __restrict__ x,
                                               const float* __restrict__ W,
                                               const float* __restrict__ bdown,
                                               float* __restrict__ ws) {
  __shared__ float xs[64][68];
  __shared__ float wls[64][68];
  const int t = threadIdx.x;
  const int row0 = blockIdx.x * 64;
  const int tx = t & 15, ty = t >> 4;

  int pr[4], pseg[4];
  #pragma unroll
  for (int it = 0; it < 4; ++it) { int c = t + it * 256; pr[it] = c >> 4; pseg[it] = c & 15; }

  float4 px[4], pw[4];
  #pragma unroll
  for (int it = 0; it < 4; ++it) {
    px[it] = *(const float4*)(x + (size_t)(row0 + pr[it]) * DM + pseg[it] * 4);
    pw[it] = *(const float4*)(W + (size_t)pr[it] * DM + pseg[it] * 4);
  }

  float acc[4][4];
  #pragma unroll
  for (int i = 0; i < 4; i++)
    #pragma unroll
    for (int j = 0; j < 4; j++) acc[i][j] = 0.f;

  for (int kt = 0; kt < 16; ++kt) {
    __syncthreads();
    #pragma unroll
    for (int it = 0; it < 4; ++it) {
      *(float4*)(&xs[pr[it]][pseg[it] * 4]) = px[it];
      *(float4*)(&wls[pr[it]][pseg[it] * 4]) = pw[it];
    }
    __syncthreads();
    if (kt < 15) {
      const int k0 = (kt + 1) * 64;
      #pragma unroll
      for (int it = 0; it < 4; ++it) {
        px[it] = *(const float4*)(x + (size_t)(row0 + pr[it]) * DM + k0 + pseg[it] * 4);
        pw[it] = *(const float4*)(W + (size_t)pr[it] * DM + k0 + pseg[it] * 4);
      }
    }
    #pragma unroll 4
    for (int k = 0; k < 64; k += 4) {
      float4 xv[4], wv[4];
      #pragma unroll
      for (int i = 0; i < 4; i++) xv[i] = *(const float4*)(&xs[ty * 4 + i][k]);
      #pragma unroll
      for (int j = 0; j < 4; j++) wv[j] = *(const float4*)(&wls[tx * 4 + j][k]);
      #pragma unroll
      for (int i = 0; i < 4; i++)
        #pragma unroll
        for (int j = 0; j < 4; j++)
          acc[i][j] = fmaf(xv[i].x, wv[j].x, fmaf(xv[i].y, wv[j].y,
                      fmaf(xv[i].z, wv[j].z, fmaf(xv[i].w, wv[j].w, acc[i][j]))));
    }
  }

  #pragma unroll
  for (int j = 0; j < 4; j++) {
    float bj = bdown[tx * 4 + j];
    #pragma unroll
    for (int i = 0; i < 4; i++) acc[i][j] += bj;
  }

  float* z = ws + WS_Z;
  float* zn2 = ws + WS_ZN2;
  #pragma unroll
  for (int i = 0; i < 4; i++) {
    float ss = acc[i][0] * acc[i][0] + acc[i][1] * acc[i][1] +
               acc[i][2] * acc[i][2] + acc[i][3] * acc[i][3];
    #pragma unroll
    for (int m = 1; m < 16; m <<= 1) ss += __shfl_xor(ss, m, 64);
    float inv = 1.0f / sqrtf(ss);
    float4 zv;
    zv.x = acc[i][0] * inv; zv.y = acc[i][1] * inv;
    zv.z = acc[i][2] * inv; zv.w = acc[i][3] * inv;
    int row = row0 + ty * 4 + i;
    *(float4*)(z + (size_t)row * CD + tx * 4) = zv;
    if (tx == 0) zn2[row] = ss * inv * inv;
  }
}

// ---- K2: distance GEMM + per-row argmin (per code-half) + column-min
// grid 512 = 256 rowtiles x 2 code-halves; 512 threads; 64 rows x 8 tiles.
__global__ __launch_bounds__(512, 4) void k2_dist(const float* __restrict__ cb,
                                                  float* __restrict__ ws) {
  __shared__ float zT[64][68];    // [d][row]
  __shared__ float cT[64][132];   // [d][code]
  __shared__ float cn2s[128];
  __shared__ float zn2s[64];
  __shared__ unsigned colmin[128];

  const int t = threadIdx.x;
  const int half = blockIdx.x & 1;
  const int row0 = (blockIdx.x >> 1) * 64;
  const int batch = row0 >> 11;
  const int tx = t & 31, ty = t >> 5;
  const float* z = ws + WS_Z;
  const float* cn2 = ws + WS_CN2;
  unsigned* cdist = (unsigned*)(ws + WS_CDIST) + (size_t)batch * KC;

  // stage zT (once)
  #pragma unroll
  for (int it = 0; it < 2; ++it) {
    int c = t + it * 512;
    int r = c >> 4, seg = c & 15;
    float4 v = *(const float4*)(z + (size_t)(row0 + r) * CD + seg * 4);
    zT[seg * 4 + 0][r] = v.x; zT[seg * 4 + 1][r] = v.y;
    zT[seg * 4 + 2][r] = v.z; zT[seg * 4 + 3][r] = v.w;
  }
  if (t < 64) zn2s[t] = (ws + WS_ZN2)[row0 + t];

  int cjj[4], cseg[4];
  #pragma unroll
  for (int it = 0; it < 4; ++it) { int c = t + it * 512; cjj[it] = c >> 4; cseg[it] = c & 15; }

  float4 pre[4];
  #pragma unroll
  for (int it = 0; it < 4; ++it) {
    int jg = half * 1024 + cjj[it];
    pre[it] = (jg < KC) ? *(const float4*)(cb + (size_t)(jg + 1) * CD + cseg[it] * 4)
                        : make_float4(0.f, 0.f, 0.f, 0.f);
  }

  float bestv[4];
  int besti[4];
  #pragma unroll
  for (int i = 0; i < 4; i++) { bestv[i] = __uint_as_float(F32_INF_BITS); besti[i] = 0; }

  for (int lt = 0; lt < 8; ++lt) {
    const int tile = half * 8 + lt;
    __syncthreads();
    #pragma unroll
    for (int it = 0; it < 4; ++it) {
      cT[cseg[it] * 4 + 0][cjj[it]] = pre[it].x;
      cT[cseg[it] * 4 + 1][cjj[it]] = pre[it].y;
      cT[cseg[it] * 4 + 2][cjj[it]] = pre[it].z;
      cT[cseg[it] * 4 + 3][cjj[it]] = pre[it].w;
    }
    if (t < 128) { cn2s[t] = cn2[tile * 128 + t]; colmin[t] = F32_INF_BITS; }
    __syncthreads();
    if (lt < 7) {
      #pragma unroll
      for (int it = 0; it < 4; ++it) {
        int jg = (tile + 1) * 128 + cjj[it];
        pre[it] = (jg < KC) ? *(const float4*)(cb + (size_t)(jg + 1) * CD + cseg[it] * 4)
                            : make_float4(0.f, 0.f, 0.f, 0.f);
      }
    }

    float dot[4][4];
    #pragma unroll
    for (int i = 0; i < 4; i++)
      #pragma unroll
      for (int j = 0; j < 4; j++) dot[i][j] = 0.f;
    #pragma unroll 8
    for (int d = 0; d < 64; ++d) {
      float4 zv = *(const float4*)(&zT[d][ty * 4]);
      float4 cv = *(const float4*)(&cT[d][tx * 4]);
      float zz[4] = {zv.x, zv.y, zv.z, zv.w};
      float cc[4] = {cv.x, cv.y, cv.z, cv.w};
      #pragma unroll
      for (int i = 0; i < 4; i++)
        #pragma unroll
        for (int j = 0; j < 4; j++) dot[i][j] = fmaf(zz[i], cc[j], dot[i][j]);
    }

    // score = cn2 - 2*dot (znorm2 constant per row: argmin-equivalent)
    #pragma unroll
    for (int jl = 0; jl < 4; jl++) {
      int jloc = tx * 4 + jl;
      int jg = tile * 128 + jloc;
      float c2 = cn2s[jloc];
      float colv = __uint_as_float(F32_INF_BITS);
      #pragma unroll
      for (int i = 0; i < 4; i++) {
        float s = fmaf(-2.f, dot[i][jl], c2);
        if (s < bestv[i]) { bestv[i] = s; besti[i] = jg; }  // ascending jg => first-index ties
        float v = zn2s[ty * 4 + i] + s;
        v = v < 0.f ? 0.f : v;        // clamp(d2,0): monotone under sqrt/min
        colv = v < colv ? v : colv;
      }
      atomicMin(&colmin[jloc], __float_as_uint(colv));
    }
    __syncthreads();
    if (t < 128) {
      int jg = tile * 128 + t;
      if (jg < KC) atomicMin(&cdist[jg], colmin[t]);
    }
  }

  // argmin reduce across the 32-lane code group (same wave)
  #pragma unroll
  for (int m = 1; m < 32; m <<= 1) {
    #pragma unroll
    for (int i = 0; i < 4; i++) {
      float ov = __shfl_xor(bestv[i], m, 64);
      int oi = __shfl_xor(besti[i], m, 64);
      if (ov < bestv[i] || (ov == bestv[i] && oi < besti[i])) { bestv[i] = ov; besti[i] = oi; }
    }
  }
  if (tx == 0) {
    #pragma unroll
    for (int i = 0; i < 4; i++) {
      int row = row0 + ty * 4 + i;
      (ws + WS_BV)[half * NROWS + row] = bestv[i];
      ((int*)(ws + WS_BI))[half * NROWS + row] = besti[i] + 1;
    }
  }
}

// ---- K2b: merge the two half-argmins (exact; half0 indices < half1)
__global__ __launch_bounds__(256) void k2b_merge(float* __restrict__ ws,
                                                 float* __restrict__ out) {
  const int row = blockIdx.x * 256 + threadIdx.x;
  float v0 = (ws + WS_BV)[row];
  float v1 = (ws + WS_BV)[NROWS + row];
  int i0 = ((const int*)(ws + WS_BI))[row];
  int i1 = ((const int*)(ws + WS_BI))[NROWS + row];
  int idx = (v1 < v0) ? i1 : i0;   // tie -> i0 (lower index) = first occurrence
  ((int*)(ws + WS_IDXM))[row] = idx;
  out[OUT_IDX + row] = (float)idx;
}

// ------- K3: gather hard codes, commitment partials, scatter sums/bincounts
__global__ __launch_bounds__(256) void k3_scatter(const float* __restrict__ cb,
                                                  float* __restrict__ ws,
                                                  float* __restrict__ out) {
  const int t = threadIdx.x;
  const int lane = t & 63;
  const int w = t >> 6;
  const int rowbase = blockIdx.x * 32 + w * 8;
  const float* z = ws + WS_Z;
  const int* idxp = (const int*)(ws + WS_IDXM);

  int idx[8];
  #pragma unroll
  for (int r = 0; r < 8; ++r) idx[r] = idxp[rowbase + r];

  float sq = 0.f;
  #pragma unroll
  for (int r = 0; r < 8; ++r) {
    const int row = rowbase + r;
    const float c = cb[(size_t)idx[r] * CD + lane];
    const float zv = z[(size_t)row * CD + lane];
    out[OUT_HARD + (size_t)row * CD + lane] = zv + (c - zv);  // matches z + sg(hard - z)
    const float d = c - zv;
    sq = fmaf(d, d, sq);
    atomicAdd(ws + WS_SUMS + (size_t)idx[r] * CD + lane, zv);
    if (lane == 0) atomicAdd((unsigned*)(ws + WS_BINC) + idx[r], 1u);
  }

  __shared__ float red[4];
  #pragma unroll
  for (int m = 1; m < 64; m <<= 1) sq += __shfl_xor(sq, m, 64);
  if (lane == 0) red[w] = sq;
  __syncthreads();
  if (t == 0) (ws + WS_COMMIT)[blockIdx.x] = red[0] + red[1] + red[2] + red[3];
}

// --------- K4a: new_cs + n + losses (single block, small data only)
__global__ __launch_bounds__(1024) void k4a_stats(const float* __restrict__ cs_in,
                                                  float* __restrict__ ws,
                                                  float* __restrict__ out) {
  __shared__ float red[1024];
  const int t = threadIdx.x;
  const unsigned* binc = (const unsigned*)(ws + WS_BINC);

  float npart = 0.f;
  #pragma unroll
  for (int i = t; i < NC; i += 1024) {
    float nc = DECAY * cs_in[i] + (1.f - DECAY) * (float)binc[i];
    out[OUT_CS + i] = nc;
    npart += nc;
  }
  red[t] = npart; __syncthreads();
  for (int s = 512; s > 0; s >>= 1) { if (t < s) red[t] += red[t + s]; __syncthreads(); }
  if (t == 0) (ws + WS_N)[0] = red[0];
  __syncthreads();

  float cpart = 0.f;
  for (int j = t; j < K3_BLOCKS; j += 1024) cpart += (ws + WS_COMMIT)[j];
  red[t] = cpart; __syncthreads();
  for (int s = 512; s > 0; s >>= 1) { if (t < s) red[t] += red[t + s]; __syncthreads(); }
  float commit = red[0]; __syncthreads();

  const unsigned* cdist = (const unsigned*)(ws + WS_CDIST);
  float lsum = 0.f, ccount = 0.f;
  for (int j = t; j < KC; j += 1024) {
    if (binc[j + 1] == 0u) {
      ccount += 1.f;
      float srow = 0.f;
      #pragma unroll
      for (int b = 0; b < NB; b++) srow += sqrtf(__uint_as_float(cdist[b * KC + j]));
      lsum += srow;
    }
  }
  red[t] = lsum; __syncthreads();
  for (int s = 512; s > 0; s >>= 1) { if (t < s) red[t] += red[t + s]; __syncthreads(); }
  float totloss = red[0]; __syncthreads();
  red[t] = ccount; __syncthreads();
  for (int s = 512; s > 0; s >>= 1) { if (t < s) red[t] += red[t + s]; __syncthreads(); }
  float cnt = red[0] * (float)NB;
  if (t == 0) {
    out[OUT_COMMIT] = commit / (float)(NROWS * CD);
    out[OUT_EMB] = totloss / fmaxf(cnt, 1.f);
  }
}

// --------- K4b: new_csum, centroids, new_cb (512 blocks x 256)
__global__ __launch_bounds__(256) void k4b_update(const float* __restrict__ cb,
                                                  const float* __restrict__ csum_in,
                                                  const float* __restrict__ ws,
                                                  float* __restrict__ out) {
  const int e = blockIdx.x * 256 + threadIdx.x;   // 0 .. NC*CD-1
  const int k = e >> 6;
  const unsigned* binc = (const unsigned*)(ws + WS_BINC);
  const float n = (ws + WS_N)[0];
  const float denom = n + (float)NC * 1e-5f;

  float ncsum = DECAY * csum_in[e] + (1.f - DECAY) * (ws + WS_SUMS)[e];
  out[OUT_CSUM + e] = ncsum;
  float smoothed = (out[OUT_CS + k] + 1e-5f) * n / denom;
  float cent = ncsum / smoothed;
  float v = (binc[k] != 0u) ? cent : cb[e];
  if (k == 0) v = 0.f;
  out[OUT_CB + e] = v;
}

extern "C" void kernel_launch(void* const* d_in, const int* in_sizes, int n_in,
                              void* d_out, int out_size, void* d_ws, size_t ws_size,
                              hipStream_t stream) {
  const float* x    = (const float*)d_in[0];
  const float* W    = (const float*)d_in[1];
  const float* b    = (const float*)d_in[2];
  const float* cb   = (const float*)d_in[3];
  const float* cs   = (const float*)d_in[4];
  const float* csum = (const float*)d_in[5];
  float* out = (float*)d_out;
  float* ws  = (float*)d_ws;

  // split-K path needs partials: (WS_PART + 4*NROWS*CD) floats
  const size_t need = ((size_t)WS_PART + (size_t)4 * NROWS * CD) * sizeof(float);
  const bool use_split = ws_size >= need;   // host-side, deterministic

  hipLaunchKernelGGL(k0_init, dim3(512), dim3(256), 0, stream, cb, ws);
  if (use_split) {
    hipLaunchKernelGGL(k1_split,  dim3(512),  dim3(512), 0, stream, x, W, ws);
    hipLaunchKernelGGL(k1_reduce, dim3(1024), dim3(256), 0, stream, b, ws);
  } else {
    hipLaunchKernelGGL(k1_down, dim3(256), dim3(256), 0, stream, x, W, b, ws);
  }
  hipLaunchKernelGGL(k2_dist,   dim3(512),       dim3(512),  0, stream, cb, ws);
  hipLaunchKernelGGL(k2b_merge, dim3(64),        dim3(256),  0, stream, ws, out);
  hipLaunchKernelGGL(k3_scatter,dim3(K3_BLOCKS), dim3(256),  0, stream, cb, ws, out);
  hipLaunchKernelGGL(k4a_stats, dim3(1),         dim3(1024), 0, stream, cs, ws, out);
  hipLaunchKernelGGL(k4b_update,dim3(512),       dim3(256),  0, stream, cb, csum, ws, out);
}